// Round 11
// baseline (88.541 us; speedup 1.0000x reference)
//
#include <hip/hip_runtime.h>

// entmax-1.5 over rows of [R=16384, N=4096] fp32.
// tau* solves f(tau) = sum_i [z_i - tau]_+^2 = 1 with z = (x - max)/2, so
// z_max = 0 and tau* in [-1,0). Newton from tau=-1 approaches the root
// monotonically from the left (f convex decreasing). Every iterate stays in
// [-1, tau*], so only elements with z > -1 (x > max - 2) can ever contribute.
//
// R4 structure (proven 75.6 us) with two deltas:
//  - prune directly at tau = -1 (no full-width Newton passes); survivors
//    K = #{x > max-2}: mean ~183, P(K > 512) ~ 3e-5  -> CAP=512, SLOTS=8
//    (R7's regression confound was CAP=256: ~6% of rows overflowed into the
//    expensive full-width fallback; this run removes that tail)
//  - survivor Newton starts at tp = 0 (~7 iters of the cheap 8-reg loop,
//    identical proven numerics: |dtau| < 1e-7 break, s2-as-normalizer)
// Everything else verbatim from R4: one wave/row, single architectural load
// of z[64], count + shfl_up scan + compact into wave-private LDS, dense
// nontemporal float4 store (write-once output bypasses cache -> input stays
// half-L3-resident across replays; FETCH 131 MB evidence).

#define ROWLEN 4096
#define ELEMS 64
#define CHUNKS 16
#define RPB 4
#define CAP 512
#define SLOTS 8

typedef float f4 __attribute__((ext_vector_type(4)));

__global__ __launch_bounds__(256) void entmax15_kernel(
    const float* __restrict__ x, float* __restrict__ out, int rows) {
    __shared__ float sv[RPB][CAP];  // wave-private survivor values, no barriers
    const int wave = threadIdx.x >> 6;
    const int lane = threadIdx.x & 63;
    const int row = blockIdx.x * RPB + wave;
    if (row >= rows) return;  // wave-uniform

    const float* __restrict__ xr = x + (size_t)row * ROWLEN;
    float* __restrict__ orow = out + (size_t)row * ROWLEN;

    // ---- Load row into registers (only HBM read of x) ----
    float z[ELEMS];
    #pragma unroll
    for (int k = 0; k < CHUNKS; ++k) {
        const float4 v = *reinterpret_cast<const float4*>(xr + (size_t)(k * 64 + lane) * 4);
        z[4 * k + 0] = v.x;
        z[4 * k + 1] = v.y;
        z[4 * k + 2] = v.z;
        z[4 * k + 3] = v.w;
    }

    // ---- Row max ----
    float m = z[0];
    #pragma unroll
    for (int i = 1; i < ELEMS; ++i) m = fmaxf(m, z[i]);
    #pragma unroll
    for (int s = 1; s < 64; s <<= 1) m = fmaxf(m, __shfl_xor(m, s, 64));
    const float mh = m * 0.5f;
    // tau = -1 baseline: s_i = z_i + 1 = fmaf(x_i, 0.5, c2), survivor iff s_i > 0
    const float c2 = 1.0f - mh;
    const float xcut = m - 2.0f;  // survivor iff x > xcut

    // ---- Count + exclusive scan (R4-proven compaction machinery) ----
    int cnt = 0;
    #pragma unroll
    for (int i = 0; i < ELEMS; ++i) cnt += (z[i] > xcut) ? 1 : 0;
    int pre = cnt;
    #pragma unroll
    for (int s = 1; s < 64; s <<= 1) {
        const int t = __shfl_up(pre, s, 64);
        if (lane >= s) pre += t;
    }
    const int K = __shfl(pre, 63, 64);  // wave-uniform (>=1: max element survives)

    float tauF, inv;
    if (K <= CAP) {
        // ---- Compact survivor values (order irrelevant) into LDS ----
        int idx = pre - cnt;
        #pragma unroll
        for (int i = 0; i < ELEMS; ++i) {
            if (z[i] > xcut) { sv[wave][idx] = fmaf(z[i], 0.5f, c2); ++idx; }
        }
        float r[SLOTS];
        #pragma unroll
        for (int j = 0; j < SLOTS; ++j) {
            const int q = lane + 64 * j;
            r[j] = (q < K) ? sv[wave][q] : -1.0f;  // pad contributes 0 for tp >= 0
        }
        // ---- Newton on survivors, tp = tau + 1 in [0, 1) ----
        float tp = 0.0f, s2f = 1.0f;
        for (int it = 0; it < 16; ++it) {
            float s1 = 0.0f, s2 = 0.0f;
            #pragma unroll
            for (int j = 0; j < SLOTS; ++j) {
                const float t = fmaxf(r[j] - tp, 0.0f);
                s1 += t;
                s2 = fmaf(t, t, s2);
            }
            #pragma unroll
            for (int s = 1; s < 64; s <<= 1) {
                s1 += __shfl_xor(s1, s, 64);
                s2 += __shfl_xor(s2, s, 64);
            }
            const float dtau = (s2 - 1.0f) / fmaxf(2.0f * s1, 1e-20f);
            s2f = s2;
            tp += dtau;
            if (fabsf(dtau) < 1e-7f) break;  // wave-uniform (identical reduce tree)
        }
        tauF = tp - 1.0f;
        inv = 1.0f / (s2f + 1e-8f);
    } else {
        // ---- Fallback (near-unreachable, P ~ 3e-5): full-width from regs ----
        float tau = -1.0f, s2f = 1.0f;
        for (int it = 0; it < 25; ++it) {
            const float c = -mh - tau;
            float s1 = 0.0f, s2 = 0.0f;
            #pragma unroll
            for (int i = 0; i < ELEMS; ++i) {
                const float t = fmaxf(fmaf(z[i], 0.5f, c), 0.0f);
                s1 += t;
                s2 = fmaf(t, t, s2);
            }
            #pragma unroll
            for (int s = 1; s < 64; s <<= 1) {
                s1 += __shfl_xor(s1, s, 64);
                s2 += __shfl_xor(s2, s, 64);
            }
            const float dtau = (s2 - 1.0f) / fmaxf(2.0f * s1, 1e-20f);
            s2f = s2;
            tau += dtau;
            if (fabsf(dtau) < 1e-7f) break;
        }
        tauF = tau;
        inv = 1.0f / (s2f + 1e-8f);
    }

    // ---- Dense output from registers, nontemporal (write-once) ----
    const float cF = -mh - tauF;
    #pragma unroll
    for (int k = 0; k < CHUNKS; ++k) {
        f4 o;
        float t;
        t = fmaxf(fmaf(z[4 * k + 0], 0.5f, cF), 0.0f); o.x = t * t * inv;
        t = fmaxf(fmaf(z[4 * k + 1], 0.5f, cF), 0.0f); o.y = t * t * inv;
        t = fmaxf(fmaf(z[4 * k + 2], 0.5f, cF), 0.0f); o.z = t * t * inv;
        t = fmaxf(fmaf(z[4 * k + 3], 0.5f, cF), 0.0f); o.w = t * t * inv;
        __builtin_nontemporal_store(o, reinterpret_cast<f4*>(orow + (size_t)(k * 64 + lane) * 4));
    }
}

extern "C" void kernel_launch(void* const* d_in, const int* in_sizes, int n_in,
                              void* d_out, int out_size, void* d_ws, size_t ws_size,
                              hipStream_t stream) {
    const float* x = (const float*)d_in[0];
    float* out = (float*)d_out;
    const int rows = in_sizes[0] / ROWLEN;  // 16384
    const int blocks = (rows + RPB - 1) / RPB;
    entmax15_kernel<<<blocks, 256, 0, stream>>>(x, out, rows);
}

// Round 12
// 75.325 us; speedup vs baseline: 1.1755x; 1.1755x over previous
//
#include <hip/hip_runtime.h>

// entmax-1.5 over rows of [R=16384, N=4096] fp32.  [R4 — proven best, 75.6 us]
// tau* solves f(tau) = sum_i [z_i - tau]_+^2 = 1 with z = (x - max)/2, so
// z_max = 0 and tau* in [-1,0). Newton from tau=-1 approaches the root
// monotonically from the left (f convex decreasing), quadratic convergence.
// One wave per row, single architectural load (compiler remats from L1/L2;
// HBM sees ~131 MB of the 256 MiB input thanks to NT-store L3 residency):
//   1. load x -> z[64] regs; max via 6-step butterfly
//   2. two full-width Newton iterations (1 fma + 1 fmax per element)
//   3. count+scan survivors (z > tau2); compact values into wave-private LDS
//   4. Newton on <=4 survivor regs/lane, break on |dtau| < 1e-7 (~5 iters)
//   5. normalizer = last s2 (exact: non-survivors contribute 0)
//   6. dense nontemporal float4 write (write-once output bypasses cache so
//      the input stays half-L3-resident across graph replays)
// Seven restructures (R5-R9, R11: earlier pruning x3, row pairing, ballot
// compaction, per-lane strips, CAP=512) all regressed. The full-width passes
// are nearly free (overlapped VALU at 25% busy) AND shrink the survivor set
// 4x, shortening the serial compact/solve chain. This structure is locally
// optimal; 85% of achievable HBM BW on its 403 MB steady-state traffic.

#define ROWLEN 4096
#define ELEMS 64
#define CHUNKS 16
#define RPB 4
#define CAP 256
#define SLOTS 4

typedef float f4 __attribute__((ext_vector_type(4)));

__global__ __launch_bounds__(256) void entmax15_kernel(
    const float* __restrict__ x, float* __restrict__ out, int rows) {
    __shared__ float sv[RPB][CAP];  // wave-private survivor values, no barriers
    const int wave = threadIdx.x >> 6;
    const int lane = threadIdx.x & 63;
    const int row = blockIdx.x * RPB + wave;
    if (row >= rows) return;  // wave-uniform

    const float* __restrict__ xr = x + (size_t)row * ROWLEN;
    float* __restrict__ orow = out + (size_t)row * ROWLEN;

    // ---- Load row into registers (only HBM read of x) ----
    float z[ELEMS];
    #pragma unroll
    for (int k = 0; k < CHUNKS; ++k) {
        const float4 v = *reinterpret_cast<const float4*>(xr + (size_t)(k * 64 + lane) * 4);
        z[4 * k + 0] = v.x;
        z[4 * k + 1] = v.y;
        z[4 * k + 2] = v.z;
        z[4 * k + 3] = v.w;
    }

    // ---- Row max ----
    float m = z[0];
    #pragma unroll
    for (int i = 1; i < ELEMS; ++i) m = fmaxf(m, z[i]);
    #pragma unroll
    for (int s = 1; s < 64; s <<= 1) m = fmaxf(m, __shfl_xor(m, s, 64));
    const float mh = m * 0.5f;  // z_i - tau = fmaf(x_i, 0.5, -mh - tau)

    // ---- Two full-width Newton iterations from tau = -1 ----
    float tau = -1.0f;
    #pragma unroll
    for (int it = 0; it < 2; ++it) {
        const float c = -mh - tau;
        float s1 = 0.0f, s2 = 0.0f;
        #pragma unroll
        for (int i = 0; i < ELEMS; ++i) {
            const float t = fmaxf(fmaf(z[i], 0.5f, c), 0.0f);
            s1 += t;
            s2 = fmaf(t, t, s2);
        }
        #pragma unroll
        for (int s = 1; s < 64; s <<= 1) {
            s1 += __shfl_xor(s1, s, 64);
            s2 += __shfl_xor(s2, s, 64);
        }
        tau += (s2 - 1.0f) / fmaxf(2.0f * s1, 1e-20f);
    }
    const float c2 = -mh - tau;
    const float xcut = -2.0f * c2;  // survivor iff x > xcut  (<=> z - tau2 > 0)

    // ---- Count + exclusive scan ----
    int cnt = 0;
    #pragma unroll
    for (int i = 0; i < ELEMS; ++i) cnt += (z[i] > xcut) ? 1 : 0;
    int pre = cnt;
    #pragma unroll
    for (int s = 1; s < 64; s <<= 1) {
        const int t = __shfl_up(pre, s, 64);
        if (lane >= s) pre += t;
    }
    const int K = __shfl(pre, 63, 64);  // wave-uniform (>=1: max element survives)

    float tauF, inv;
    if (K <= CAP) {
        // ---- Compact survivor values (order irrelevant) into LDS ----
        int idx = pre - cnt;
        #pragma unroll
        for (int i = 0; i < ELEMS; ++i) {
            if (z[i] > xcut) { sv[wave][idx] = fmaf(z[i], 0.5f, c2); ++idx; }
        }
        float r[SLOTS];
        #pragma unroll
        for (int j = 0; j < SLOTS; ++j) {
            const int q = lane + 64 * j;
            r[j] = (q < K) ? sv[wave][q] : -1.0f;  // pad contributes 0 for tp >= 0
        }
        // ---- Newton on survivors, tp = tau - tau2 >= 0 ----
        float tp = 0.0f, s2f = 1.0f;
        for (int it = 0; it < 10; ++it) {
            float s1 = 0.0f, s2 = 0.0f;
            #pragma unroll
            for (int j = 0; j < SLOTS; ++j) {
                const float t = fmaxf(r[j] - tp, 0.0f);
                s1 += t;
                s2 = fmaf(t, t, s2);
            }
            #pragma unroll
            for (int s = 1; s < 64; s <<= 1) {
                s1 += __shfl_xor(s1, s, 64);
                s2 += __shfl_xor(s2, s, 64);
            }
            const float dtau = (s2 - 1.0f) / fmaxf(2.0f * s1, 1e-20f);
            s2f = s2;
            tp += dtau;
            if (fabsf(dtau) < 1e-7f) break;  // wave-uniform (identical reduce tree)
        }
        tauF = tau + tp;
        inv = 1.0f / (s2f + 1e-8f);
    } else {
        // ---- Fallback (adversarial rows): continue full-width from regs ----
        float s2f = 1.0f;
        for (int it = 0; it < 20; ++it) {
            const float c = -mh - tau;
            float s1 = 0.0f, s2 = 0.0f;
            #pragma unroll
            for (int i = 0; i < ELEMS; ++i) {
                const float t = fmaxf(fmaf(z[i], 0.5f, c), 0.0f);
                s1 += t;
                s2 = fmaf(t, t, s2);
            }
            #pragma unroll
            for (int s = 1; s < 64; s <<= 1) {
                s1 += __shfl_xor(s1, s, 64);
                s2 += __shfl_xor(s2, s, 64);
            }
            const float dtau = (s2 - 1.0f) / fmaxf(2.0f * s1, 1e-20f);
            s2f = s2;
            tau += dtau;
            if (fabsf(dtau) < 1e-7f) break;
        }
        tauF = tau;
        inv = 1.0f / (s2f + 1e-8f);
    }

    // ---- Dense output from registers, nontemporal (write-once) ----
    const float cF = -mh - tauF;
    #pragma unroll
    for (int k = 0; k < CHUNKS; ++k) {
        f4 o;
        float t;
        t = fmaxf(fmaf(z[4 * k + 0], 0.5f, cF), 0.0f); o.x = t * t * inv;
        t = fmaxf(fmaf(z[4 * k + 1], 0.5f, cF), 0.0f); o.y = t * t * inv;
        t = fmaxf(fmaf(z[4 * k + 2], 0.5f, cF), 0.0f); o.z = t * t * inv;
        t = fmaxf(fmaf(z[4 * k + 3], 0.5f, cF), 0.0f); o.w = t * t * inv;
        __builtin_nontemporal_store(o, reinterpret_cast<f4*>(orow + (size_t)(k * 64 + lane) * 4));
    }
}

extern "C" void kernel_launch(void* const* d_in, const int* in_sizes, int n_in,
                              void* d_out, int out_size, void* d_ws, size_t ws_size,
                              hipStream_t stream) {
    const float* x = (const float*)d_in[0];
    float* out = (float*)d_out;
    const int rows = in_sizes[0] / ROWLEN;  // 16384
    const int blocks = (rows + RPB - 1) / RPB;
    entmax15_kernel<<<blocks, 256, 0, stream>>>(x, out, rows);
}